// Round 10
// baseline (50.330 us; speedup 1.0000x reference)
//
#include <hip/hip_runtime.h>
#include <math.h>

typedef float f32x16 __attribute__((ext_vector_type(16)));
typedef __bf16 bf16x8 __attribute__((ext_vector_type(8)));

constexpr int DEG = 64;
constexpr int KC  = 32;
constexpr int D   = 64;
constexpr float EPS = 1.1920929e-05f;  // 100 * f32 eps

// LDS layout (hi only): row-major [64 rows][8 chunks of 16B], chunk c of row r
// at slot (c ^ (r&7)) -> ushort idx = row*64 + slot*8. Staged via
// global_load_lds with pre-permuted SOURCE chunk sc=(l&7)^(l>>3), linear dest.
__device__ __forceinline__ int yidx(int row, int c) {
    return (row << 6) + (((c ^ (row & 7)) & 7) << 3);
}

// ---------------- prep: x(f32) -> xhi/xlo(bf16, row-major) + row norms ----------------
__global__ __launch_bounds__(256)
void rgc_prep(const float* __restrict__ x,
              unsigned short* __restrict__ xhi,
              unsigned short* __restrict__ xlo,
              float* __restrict__ xnrm, int nrows) {
    const int id  = blockIdx.x * 256 + threadIdx.x;
    const int row = id >> 3;
    const int c   = id & 7;
    if (row >= nrows) return;
    const float* src = x + ((size_t)row << 6) + (c << 3);
    const float4 v0 = *reinterpret_cast<const float4*>(src);
    const float4 v1 = *reinterpret_cast<const float4*>(src + 4);
    const float fv[8] = {v0.x, v0.y, v0.z, v0.w, v1.x, v1.y, v1.z, v1.w};
    bf16x8 h, e;
    float s = 0.f;
    #pragma unroll
    for (int j = 0; j < 8; ++j) {
        const float f = fv[j];
        s += f * f;
        const __bf16 hb = (__bf16)f;   // RNE
        h[j] = hb;
        e[j] = (__bf16)(f - (float)hb);
    }
    s += __shfl_xor(s, 1); s += __shfl_xor(s, 2); s += __shfl_xor(s, 4);
    if (c == 0) xnrm[row] = s;
    const size_t o = ((size_t)row << 6) + (c << 3);
    *reinterpret_cast<bf16x8*>(xhi + o) = h;
    *reinterpret_cast<bf16x8*>(xlo + o) = e;
}

// ------- main: 2 independent waves/block (2 nodes), 8 KB LDS each, no barriers -------
// Norms folded into MFMA via augmented K-slab: acc = dot - 0.5*(nm+nk),
// so sq = -2*acc and the m-reduction needs NO cross-lane norm reads.
__global__ __launch_bounds__(128, 4)
void rgc_main(const unsigned short* __restrict__ xhi,
              const unsigned short* __restrict__ xlo,
              const float* __restrict__ xnrm,
              const int*   __restrict__ nbr,
              float*       __restrict__ out) {
    __shared__ __align__(16) unsigned short yh[2][4096];  // 8 KB per wave

    const int t  = threadIdx.x;
    const int wv = t >> 6;
    const int l  = t & 63;
    const long node = (long)blockIdx.x * 2 + wv;

    const int   my = nbr[node * 64 + l];
    const float nr = xnrm[my];          // lane l = norm of neighbor-row l

    const int frow = l & 31;
    const int kh   = l >> 5;

    // ---- lo fragments: direct per-lane gathers (issued early, overlap staging) ----
    const int gb = __shfl(my, frow);          // k rows 0..31 (also tile0 m rows)
    const int ga = __shfl(my, 32 + frow);     // tile1 m rows 32..63
    bf16x8 blx[4], alx[4];
    #pragma unroll
    for (int s = 0; s < 4; ++s) {
        blx[s] = *reinterpret_cast<const bf16x8*>(xlo + ((size_t)gb << 6) + ((2 * s + kh) << 3));
        alx[s] = *reinterpret_cast<const bf16x8*>(xlo + ((size_t)ga << 6) + ((2 * s + kh) << 3));
    }

    // ---- augmented-slab fragments (dims 64,65): A=[nm,1], B=[-0.5,-0.5*nk] ----
    const float nk = __shfl(nr, frow);        // norm of k-row frow (= tile0 nm)
    const float na = __shfl(nr, 32 + frow);   // norm of tile1 m-row
    bf16x8 Bh = {}, Bl = {}, A0h = {}, A0l = {}, A1h = {}, A1l = {};
    {
        const float mnk = -0.5f * nk;
        const __bf16 mnk_h = (__bf16)mnk;
        const __bf16 mnk_l = (__bf16)(mnk - (float)mnk_h);
        const __bf16 nk_h  = (__bf16)nk;
        const __bf16 nk_l  = (__bf16)(nk - (float)nk_h);
        const __bf16 na_h  = (__bf16)na;
        const __bf16 na_l  = (__bf16)(na - (float)na_h);
        if (kh == 0) {   // aug dims live in the kh=0 element slots
            Bh[0] = (__bf16)(-0.5f); Bh[1] = mnk_h; Bl[1] = mnk_l;
            A0h[0] = nk_h; A0h[1] = (__bf16)1.0f; A0l[0] = nk_l;
            A1h[0] = na_h; A1h[1] = (__bf16)1.0f; A1l[0] = na_l;
        }
    }

    // ---- hi staging: instr j covers rows 8j..8j+7 fully (16 lines/instr) ----
    unsigned short* yb = &yh[wv][0];
    const int sc = (l & 7) ^ (l >> 3);   // source chunk -> lands at slot l&7
    #pragma unroll
    for (int j = 0; j < 8; ++j) {
        const int g = __shfl(my, 8 * j + (l >> 3));
        const size_t so = ((size_t)g << 6) + (sc << 3);
        __builtin_amdgcn_global_load_lds(
            (const __attribute__((address_space(1))) unsigned int*)(xhi + so),
            (__attribute__((address_space(3))) unsigned int*)(yb + (j << 9)),
            16, 0, 0);
    }
    asm volatile("s_waitcnt vmcnt(0)" ::: "memory");
    __builtin_amdgcn_sched_barrier(0);
    // waves are independent: no s_barrier anywhere

    // ---- hi fragments from LDS ----
    bf16x8 bh[4], ah2[4];
    #pragma unroll
    for (int s = 0; s < 4; ++s) {
        const int c = 2 * s + kh;
        bh[s]  = *reinterpret_cast<const bf16x8*>(&yb[yidx(frow, c)]);
        ah2[s] = *reinterpret_cast<const bf16x8*>(&yb[yidx(32 + frow, c)]);
    }

    // ---- Gram + norms: D = Xm·Xk^T - 0.5(nm+nk); k = lane dim, m = reg dim ----
    f32x16 acc0 = {}, acc1 = {};
    #pragma unroll
    for (int s = 0; s < 4; ++s) {
        acc0 = __builtin_amdgcn_mfma_f32_32x32x16_bf16(bh[s],  bh[s],  acc0, 0, 0, 0);
        acc1 = __builtin_amdgcn_mfma_f32_32x32x16_bf16(ah2[s], bh[s],  acc1, 0, 0, 0);
    }
    #pragma unroll
    for (int s = 0; s < 4; ++s) {
        acc0 = __builtin_amdgcn_mfma_f32_32x32x16_bf16(bh[s],  blx[s], acc0, 0, 0, 0);
        acc1 = __builtin_amdgcn_mfma_f32_32x32x16_bf16(ah2[s], blx[s], acc1, 0, 0, 0);
    }
    #pragma unroll
    for (int s = 0; s < 4; ++s) {
        acc0 = __builtin_amdgcn_mfma_f32_32x32x16_bf16(blx[s], bh[s],  acc0, 0, 0, 0);
        acc1 = __builtin_amdgcn_mfma_f32_32x32x16_bf16(alx[s], bh[s],  acc1, 0, 0, 0);
    }
    // augmented slab: hihi, hilo, lohi (A_lo·B_lo is structurally 0)
    acc0 = __builtin_amdgcn_mfma_f32_32x32x16_bf16(A0h, Bh, acc0, 0, 0, 0);
    acc1 = __builtin_amdgcn_mfma_f32_32x32x16_bf16(A1h, Bh, acc1, 0, 0, 0);
    acc0 = __builtin_amdgcn_mfma_f32_32x32x16_bf16(A0h, Bl, acc0, 0, 0, 0);
    acc1 = __builtin_amdgcn_mfma_f32_32x32x16_bf16(A1h, Bl, acc1, 0, 0, 0);
    acc0 = __builtin_amdgcn_mfma_f32_32x32x16_bf16(A0l, Bh, acc0, 0, 0, 0);
    acc1 = __builtin_amdgcn_mfma_f32_32x32x16_bf16(A1l, Bh, acc1, 0, 0, 0);

    // ---- l2 + dist: sq = -2*acc -> |sq|+EPS = 2|acc|+EPS; no cross-lane reads ----
    float s = 0.f;
    #pragma unroll
    for (int r = 0; r < 16; ++r)
        s += __builtin_amdgcn_sqrtf(__builtin_fmaf(2.0f, __builtin_fabsf(acc0[r]), EPS));
    #pragma unroll
    for (int r = 0; r < 16; ++r)
        s += __builtin_amdgcn_sqrtf(__builtin_fmaf(2.0f, __builtin_fabsf(acc1[r]), EPS));
    s += __shfl_xor(s, 32);   // full dist_k at lanes k and k+32

    // ---- softmax over 32 candidates (in-wave, replicated across halves) ----
    float dmin = s;
    #pragma unroll
    for (int m = 1; m <= 16; m <<= 1) dmin = fminf(dmin, __shfl_xor(dmin, m));
    const float ez = __expf(dmin - s);
    float Z = ez;
    #pragma unroll
    for (int m = 1; m <= 16; m <<= 1) Z += __shfl_xor(Z, m);
    const float ezs = ez * (64.0f / Z);   // lane k holds w_k (row_sum = DEG)

    // ---- output (hi-only reconstruction): lane l -> d-pair (2*(l&31), +1) ----
    const int d0 = (l & 31) << 1;
    float oe = 0.f, oo = 0.f;
    #pragma unroll
    for (int kk = 0; kk < 16; ++kk) {
        const int k  = (kh << 4) + kk;
        const float wk = __shfl(ezs, k);
        const int idx = (k << 6) + ((((d0 >> 3) ^ (k & 7)) & 7) << 3) + (d0 & 7);
        const unsigned uh = *reinterpret_cast<const unsigned*>(&yb[idx]);
        oe = __builtin_fmaf(wk, __uint_as_float(uh << 16), oe);
        oo = __builtin_fmaf(wk, __uint_as_float(uh & 0xffff0000u), oo);
    }
    oe += __shfl_xor(oe, 32);
    oo += __shfl_xor(oo, 32);
    if (l < 32) {
        float2 v = make_float2(oe, oo);
        *reinterpret_cast<float2*>(out + ((size_t)node << 6) + (l << 1)) = v;
    }
}

// ---------------- fallback (no workspace): R4 path ----------------
__device__ __forceinline__ int yidx_cm(int row, int chunk) {  // old chunk-major
    return (chunk << 9) + ((row ^ chunk) << 3);
}

__global__ __launch_bounds__(128, 4)
void rgc_fallback(const float* __restrict__ x,
                  const int*   __restrict__ nbr,
                  float*       __restrict__ out) {
    __shared__ __align__(16) unsigned short yhi[4096];
    __shared__ __align__(16) unsigned short ylo[4096];
    __shared__ float nrm[64];
    __shared__ float wsh[KC];
    __shared__ float pdist[64];
    __shared__ float obuf[64];

    const int n = blockIdx.x;
    const int t = threadIdx.x;
    const int w = t >> 6;
    const int l = t & 63;

    const int srow = t >> 3;
    const int sc   = t & 7;
    int gidx[4];
    #pragma unroll
    for (int it = 0; it < 4; ++it)
        gidx[it] = nbr[(n << 6) + it * 16 + srow];

    #pragma unroll
    for (int it = 0; it < 4; ++it) {
        const int row = it * 16 + srow;
        const float* src = x + ((size_t)gidx[it] << 6) + (sc << 3);
        const float4 v0 = *reinterpret_cast<const float4*>(src);
        const float4 v1 = *reinterpret_cast<const float4*>(src + 4);
        const float fv[8] = {v0.x, v0.y, v0.z, v0.w, v1.x, v1.y, v1.z, v1.w};
        float s = 0.f;
        bf16x8 h, e;
        #pragma unroll
        for (int j = 0; j < 8; ++j) {
            const float f = fv[j];
            s += f * f;
            const __bf16 hb = (__bf16)f;
            h[j] = hb;
            e[j] = (__bf16)(f - (float)hb);
        }
        s += __shfl_xor(s, 1); s += __shfl_xor(s, 2); s += __shfl_xor(s, 4);
        if (sc == 0) nrm[row] = s;
        const int base = yidx_cm(row, sc);
        *reinterpret_cast<bf16x8*>(&yhi[base]) = h;
        *reinterpret_cast<bf16x8*>(&ylo[base]) = e;
    }
    __syncthreads();

    const int frow = l & 31;
    const int kh   = l >> 5;
    bf16x8 amh[4], aml[4], bkh[4], bkl[4];
    #pragma unroll
    for (int s = 0; s < 4; ++s) {
        const int c  = 2 * s + kh;
        const int kb = yidx_cm(frow, c);
        bkh[s] = *reinterpret_cast<bf16x8*>(&yhi[kb]);
        bkl[s] = *reinterpret_cast<bf16x8*>(&ylo[kb]);
    }
    if (w == 0) {
        #pragma unroll
        for (int s = 0; s < 4; ++s) { amh[s] = bkh[s]; aml[s] = bkl[s]; }
    } else {
        #pragma unroll
        for (int s = 0; s < 4; ++s) {
            const int c  = 2 * s + kh;
            const int mb = yidx_cm(32 + frow, c);
            amh[s] = *reinterpret_cast<bf16x8*>(&yhi[mb]);
            aml[s] = *reinterpret_cast<bf16x8*>(&ylo[mb]);
        }
    }

    f32x16 acc = {};
    #pragma unroll
    for (int s = 0; s < 4; ++s)
        acc = __builtin_amdgcn_mfma_f32_32x32x16_bf16(amh[s], bkh[s], acc, 0, 0, 0);
    #pragma unroll
    for (int s = 0; s < 4; ++s)
        acc = __builtin_amdgcn_mfma_f32_32x32x16_bf16(amh[s], bkl[s], acc, 0, 0, 0);
    #pragma unroll
    for (int s = 0; s < 4; ++s)
        acc = __builtin_amdgcn_mfma_f32_32x32x16_bf16(aml[s], bkh[s], acc, 0, 0, 0);

    const float nk  = nrm[frow];
    const int   mb0 = w * 32 + 4 * kh;
    float s = 0.f;
    #pragma unroll
    for (int r = 0; r < 16; ++r) {
        const float nm = nrm[mb0 + (r & 3) + 8 * (r >> 2)];
        const float sq = __builtin_fmaf(-2.0f, acc[r], nm + nk);
        s += __builtin_amdgcn_sqrtf(__builtin_fabsf(sq) + EPS);
    }
    s += __shfl_xor(s, 32);
    if (l < 32) pdist[w * 32 + l] = s;
    __syncthreads();

    const float dsum = pdist[frow] + pdist[32 + frow];
    float dmin = dsum;
    #pragma unroll
    for (int m = 1; m <= 16; m <<= 1) dmin = fminf(dmin, __shfl_xor(dmin, m));
    const float ez = __expf(dmin - dsum);
    float Z = ez;
    #pragma unroll
    for (int m = 1; m <= 16; m <<= 1) Z += __shfl_xor(Z, m);
    if (t < 32) wsh[frow] = ez * (64.0f / Z);
    __syncthreads();

    const int oc = l >> 3;
    const int ow = l & 7;
    float o = 0.f;
    #pragma unroll
    for (int kk = 0; kk < 16; ++kk) {
        const int kx = w * 16 + kk;
        const int bi = yidx_cm(kx, oc) + ow;
        const float f = __uint_as_float((unsigned)yhi[bi] << 16)
                      + __uint_as_float((unsigned)ylo[bi] << 16);
        o += wsh[kx] * f;
    }
    if (w == 1) obuf[l] = o;
    __syncthreads();
    if (w == 0) out[(size_t)n * D + l] = o + obuf[l];
}

extern "C" void kernel_launch(void* const* d_in, const int* in_sizes, int n_in,
                              void* d_out, int out_size, void* d_ws, size_t ws_size,
                              hipStream_t stream) {
    const float* x   = (const float*)d_in[0];
    const int*   nbr = (const int*)d_in[1];
    float*       out = (float*)d_out;
    const int n_nodes = in_sizes[0] / D;   // 20000
    const size_t need = (size_t)n_nodes * D * 2 * sizeof(unsigned short)
                      + (size_t)n_nodes * sizeof(float);
    if (d_ws != nullptr && ws_size >= need && (n_nodes % 2) == 0) {
        unsigned short* xhi  = (unsigned short*)d_ws;
        unsigned short* xlo  = xhi + (size_t)n_nodes * D;
        float*          xnrm = (float*)(xlo + (size_t)n_nodes * D);
        const int tasks = n_nodes * 8;
        rgc_prep<<<(tasks + 255) / 256, 256, 0, stream>>>(x, xhi, xlo, xnrm, n_nodes);
        rgc_main<<<n_nodes / 2, 128, 0, stream>>>(xhi, xlo, xnrm, nbr, out);
    } else {
        rgc_fallback<<<n_nodes, 128, 0, stream>>>(x, nbr, out);
    }
}

// Round 11
// 46.057 us; speedup vs baseline: 1.0928x; 1.0928x over previous
//
#include <hip/hip_runtime.h>
#include <math.h>

typedef float f32x16 __attribute__((ext_vector_type(16)));
typedef __bf16 bf16x8 __attribute__((ext_vector_type(8)));

constexpr int DEG = 64;
constexpr int KC  = 32;
constexpr int D   = 64;
constexpr float EPS = 1.1920929e-05f;  // 100 * f32 eps

// LDS layout (hi only): row-major [64 rows][8 chunks of 16B], chunk c of row r
// at slot (c ^ (r&7)) -> ushort idx = row*64 + slot*8. Staged via
// global_load_lds with pre-permuted SOURCE chunk sc=(l&7)^(l>>3), linear dest.
__device__ __forceinline__ int yidx(int row, int c) {
    return (row << 6) + (((c ^ (row & 7)) & 7) << 3);
}

// ---------------- prep: x(f32) -> xhi/xlo(bf16, row-major) + row norms ----------------
__global__ __launch_bounds__(256)
void rgc_prep(const float* __restrict__ x,
              unsigned short* __restrict__ xhi,
              unsigned short* __restrict__ xlo,
              float* __restrict__ xnrm, int nrows) {
    const int id  = blockIdx.x * 256 + threadIdx.x;
    const int row = id >> 3;
    const int c   = id & 7;
    if (row >= nrows) return;
    const float* src = x + ((size_t)row << 6) + (c << 3);
    const float4 v0 = *reinterpret_cast<const float4*>(src);
    const float4 v1 = *reinterpret_cast<const float4*>(src + 4);
    const float fv[8] = {v0.x, v0.y, v0.z, v0.w, v1.x, v1.y, v1.z, v1.w};
    bf16x8 h, e;
    float s = 0.f;
    #pragma unroll
    for (int j = 0; j < 8; ++j) {
        const float f = fv[j];
        s += f * f;
        const __bf16 hb = (__bf16)f;   // RNE
        h[j] = hb;
        e[j] = (__bf16)(f - (float)hb);
    }
    s += __shfl_xor(s, 1); s += __shfl_xor(s, 2); s += __shfl_xor(s, 4);
    if (c == 0) xnrm[row] = s;
    const size_t o = ((size_t)row << 6) + (c << 3);
    *reinterpret_cast<bf16x8*>(xhi + o) = h;
    *reinterpret_cast<bf16x8*>(xlo + o) = e;
}

// ------- main: 2 independent waves/block (2 nodes), 8 KB LDS each, no barriers -------
// Norms folded into a single aug MFMA per tile; split vmcnt join for early MFMA start;
// epilogue weights via LDS broadcast table (no shfl chain).
__global__ __launch_bounds__(128, 4)
void rgc_main(const unsigned short* __restrict__ xhi,
              const unsigned short* __restrict__ xlo,
              const float* __restrict__ xnrm,
              const int*   __restrict__ nbr,
              float*       __restrict__ out) {
    __shared__ __align__(16) unsigned short yh[2][4096];  // 8 KB per wave
    __shared__ __align__(16) float wtab[2][32];           // per-wave softmax weights

    const int t  = threadIdx.x;
    const int wv = t >> 6;
    const int l  = t & 63;
    const long node = (long)blockIdx.x * 2 + wv;

    const int my = nbr[node * 64 + l];

    const int frow = l & 31;
    const int kh   = l >> 5;

    // ---- hi staging FIRST: instr j covers rows 8j..8j+7 fully (16 lines/instr) ----
    unsigned short* yb = &yh[wv][0];
    const int sc = (l & 7) ^ (l >> 3);   // source chunk -> lands at slot l&7
    #pragma unroll
    for (int j = 0; j < 8; ++j) {
        const int g = __shfl(my, 8 * j + (l >> 3));
        const size_t so = ((size_t)g << 6) + (sc << 3);
        __builtin_amdgcn_global_load_lds(
            (const __attribute__((address_space(1))) unsigned int*)(xhi + so),
            (__attribute__((address_space(3))) unsigned int*)(yb + (j << 9)),
            16, 0, 0);
    }
    __builtin_amdgcn_sched_barrier(0);   // pin: staging issued before lo/xnrm loads

    // ---- lo fragments + norms: plain loads (compiler-tracked waits) ----
    const int gb = __shfl(my, frow);          // k rows 0..31 (also tile0 m rows)
    const int ga = __shfl(my, 32 + frow);     // tile1 m rows 32..63
    bf16x8 blx[4], alx[4];
    #pragma unroll
    for (int s = 0; s < 4; ++s) {
        blx[s] = *reinterpret_cast<const bf16x8*>(xlo + ((size_t)gb << 6) + ((2 * s + kh) << 3));
        alx[s] = *reinterpret_cast<const bf16x8*>(xlo + ((size_t)ga << 6) + ((2 * s + kh) << 3));
    }
    const float nk = xnrm[gb];   // norm of k-row frow (= tile0 m-row norm)
    const float na = xnrm[ga];   // norm of tile1 m-row
    __builtin_amdgcn_sched_barrier(0);   // pin: all plain loads issued here

    // stage(8) + lo(8) + nk,na(2) outstanding <= 18; vmcnt(10) drains the 8 staging
    asm volatile("s_waitcnt vmcnt(10)" ::: "memory");
    __builtin_amdgcn_sched_barrier(0);

    // ---- hi fragments from LDS (staging complete) ----
    bf16x8 bh[4], ah2[4];
    #pragma unroll
    for (int s = 0; s < 4; ++s) {
        const int c = 2 * s + kh;
        bh[s]  = *reinterpret_cast<const bf16x8*>(&yb[yidx(frow, c)]);
        ah2[s] = *reinterpret_cast<const bf16x8*>(&yb[yidx(32 + frow, c)]);
    }

    // ---- hi*hi MFMAs start while lo loads are still landing ----
    f32x16 acc0 = {}, acc1 = {};
    #pragma unroll
    for (int s = 0; s < 4; ++s) {
        acc0 = __builtin_amdgcn_mfma_f32_32x32x16_bf16(bh[s],  bh[s], acc0, 0, 0, 0);
        acc1 = __builtin_amdgcn_mfma_f32_32x32x16_bf16(ah2[s], bh[s], acc1, 0, 0, 0);
    }

    // ---- single aug slab: A=[nm_h,nm_l,1,1], B=[-0.5,-0.5,mnk_h,mnk_l] ----
    // acc += -0.5*(nm+nk); -0.5*bf16 products are exact, mnk hi/lo to 2^-19.
    bf16x8 Bg = {}, A0 = {}, A1 = {};
    {
        const float mnk = -0.5f * nk;
        const __bf16 mnk_h = (__bf16)mnk;
        if (kh == 0) {
            Bg[0] = (__bf16)(-0.5f); Bg[1] = (__bf16)(-0.5f);
            Bg[2] = mnk_h;           Bg[3] = (__bf16)(mnk - (float)mnk_h);
            const __bf16 nk_h = (__bf16)nk;
            A0[0] = nk_h; A0[1] = (__bf16)(nk - (float)nk_h);
            A0[2] = (__bf16)1.0f; A0[3] = (__bf16)1.0f;
            const __bf16 na_h = (__bf16)na;
            A1[0] = na_h; A1[1] = (__bf16)(na - (float)na_h);
            A1[2] = (__bf16)1.0f; A1[3] = (__bf16)1.0f;
        }
    }
    acc0 = __builtin_amdgcn_mfma_f32_32x32x16_bf16(A0, Bg, acc0, 0, 0, 0);
    acc1 = __builtin_amdgcn_mfma_f32_32x32x16_bf16(A1, Bg, acc1, 0, 0, 0);

    // ---- cross terms (compiler inserts vmcnt for blx/alx) ----
    #pragma unroll
    for (int s = 0; s < 4; ++s) {
        acc0 = __builtin_amdgcn_mfma_f32_32x32x16_bf16(bh[s],  blx[s], acc0, 0, 0, 0);
        acc1 = __builtin_amdgcn_mfma_f32_32x32x16_bf16(ah2[s], blx[s], acc1, 0, 0, 0);
    }
    #pragma unroll
    for (int s = 0; s < 4; ++s) {
        acc0 = __builtin_amdgcn_mfma_f32_32x32x16_bf16(blx[s], bh[s], acc0, 0, 0, 0);
        acc1 = __builtin_amdgcn_mfma_f32_32x32x16_bf16(alx[s], bh[s], acc1, 0, 0, 0);
    }

    // ---- l2 + dist: sq = -2*acc -> |sq|+EPS = 2|acc|+EPS; 4-way sum tree ----
    float s0 = 0.f, s1 = 0.f, s2 = 0.f, s3 = 0.f;
    #pragma unroll
    for (int r = 0; r < 16; r += 4) {
        s0 += __builtin_amdgcn_sqrtf(__builtin_fmaf(2.0f, __builtin_fabsf(acc0[r + 0]), EPS));
        s1 += __builtin_amdgcn_sqrtf(__builtin_fmaf(2.0f, __builtin_fabsf(acc0[r + 1]), EPS));
        s2 += __builtin_amdgcn_sqrtf(__builtin_fmaf(2.0f, __builtin_fabsf(acc0[r + 2]), EPS));
        s3 += __builtin_amdgcn_sqrtf(__builtin_fmaf(2.0f, __builtin_fabsf(acc0[r + 3]), EPS));
    }
    #pragma unroll
    for (int r = 0; r < 16; r += 4) {
        s0 += __builtin_amdgcn_sqrtf(__builtin_fmaf(2.0f, __builtin_fabsf(acc1[r + 0]), EPS));
        s1 += __builtin_amdgcn_sqrtf(__builtin_fmaf(2.0f, __builtin_fabsf(acc1[r + 1]), EPS));
        s2 += __builtin_amdgcn_sqrtf(__builtin_fmaf(2.0f, __builtin_fabsf(acc1[r + 2]), EPS));
        s3 += __builtin_amdgcn_sqrtf(__builtin_fmaf(2.0f, __builtin_fabsf(acc1[r + 3]), EPS));
    }
    float s = (s0 + s1) + (s2 + s3);
    s += __shfl_xor(s, 32);   // full dist_k at lanes k and k+32

    // ---- softmax over 32 candidates (in-wave, replicated across halves) ----
    float dmin = s;
    #pragma unroll
    for (int m = 1; m <= 16; m <<= 1) dmin = fminf(dmin, __shfl_xor(dmin, m));
    const float ez = __expf(dmin - s);
    float Z = ez;
    #pragma unroll
    for (int m = 1; m <= 16; m <<= 1) Z += __shfl_xor(Z, m);
    const float ezs = ez * (64.0f / Z);   // lane k holds w_k (row_sum = DEG)

    // ---- epilogue: w via LDS broadcast table (kills the shfl chain) ----
    if (l < 32) wtab[wv][l] = ezs;
    asm volatile("s_waitcnt lgkmcnt(0)" ::: "memory");
    __builtin_amdgcn_sched_barrier(0);

    const int klo = kh << 4;
    const float4 w0 = *reinterpret_cast<const float4*>(&wtab[wv][klo + 0]);
    const float4 w1 = *reinterpret_cast<const float4*>(&wtab[wv][klo + 4]);
    const float4 w2 = *reinterpret_cast<const float4*>(&wtab[wv][klo + 8]);
    const float4 w3 = *reinterpret_cast<const float4*>(&wtab[wv][klo + 12]);
    const float wreg[16] = {w0.x, w0.y, w0.z, w0.w, w1.x, w1.y, w1.z, w1.w,
                            w2.x, w2.y, w2.z, w2.w, w3.x, w3.y, w3.z, w3.w};

    const int d0 = (l & 31) << 1;
    float oe = 0.f, oo = 0.f;
    #pragma unroll
    for (int kk = 0; kk < 16; ++kk) {
        const int k  = klo + kk;
        const float wk = wreg[kk];
        const int idx = (k << 6) + ((((d0 >> 3) ^ (k & 7)) & 7) << 3) + (d0 & 7);
        const unsigned uh = *reinterpret_cast<const unsigned*>(&yb[idx]);
        oe = __builtin_fmaf(wk, __uint_as_float(uh << 16), oe);
        oo = __builtin_fmaf(wk, __uint_as_float(uh & 0xffff0000u), oo);
    }
    oe += __shfl_xor(oe, 32);
    oo += __shfl_xor(oo, 32);
    if (l < 32) {
        float2 v = make_float2(oe, oo);
        *reinterpret_cast<float2*>(out + ((size_t)node << 6) + (l << 1)) = v;
    }
}

// ---------------- fallback (no workspace): R4 path ----------------
__device__ __forceinline__ int yidx_cm(int row, int chunk) {  // old chunk-major
    return (chunk << 9) + ((row ^ chunk) << 3);
}

__global__ __launch_bounds__(128, 4)
void rgc_fallback(const float* __restrict__ x,
                  const int*   __restrict__ nbr,
                  float*       __restrict__ out) {
    __shared__ __align__(16) unsigned short yhi[4096];
    __shared__ __align__(16) unsigned short ylo[4096];
    __shared__ float nrm[64];
    __shared__ float wsh[KC];
    __shared__ float pdist[64];
    __shared__ float obuf[64];

    const int n = blockIdx.x;
    const int t = threadIdx.x;
    const int w = t >> 6;
    const int l = t & 63;

    const int srow = t >> 3;
    const int sc   = t & 7;
    int gidx[4];
    #pragma unroll
    for (int it = 0; it < 4; ++it)
        gidx[it] = nbr[(n << 6) + it * 16 + srow];

    #pragma unroll
    for (int it = 0; it < 4; ++it) {
        const int row = it * 16 + srow;
        const float* src = x + ((size_t)gidx[it] << 6) + (sc << 3);
        const float4 v0 = *reinterpret_cast<const float4*>(src);
        const float4 v1 = *reinterpret_cast<const float4*>(src + 4);
        const float fv[8] = {v0.x, v0.y, v0.z, v0.w, v1.x, v1.y, v1.z, v1.w};
        float s = 0.f;
        bf16x8 h, e;
        #pragma unroll
        for (int j = 0; j < 8; ++j) {
            const float f = fv[j];
            s += f * f;
            const __bf16 hb = (__bf16)f;
            h[j] = hb;
            e[j] = (__bf16)(f - (float)hb);
        }
        s += __shfl_xor(s, 1); s += __shfl_xor(s, 2); s += __shfl_xor(s, 4);
        if (sc == 0) nrm[row] = s;
        const int base = yidx_cm(row, sc);
        *reinterpret_cast<bf16x8*>(&yhi[base]) = h;
        *reinterpret_cast<bf16x8*>(&ylo[base]) = e;
    }
    __syncthreads();

    const int frow = l & 31;
    const int kh   = l >> 5;
    bf16x8 amh[4], aml[4], bkh[4], bkl[4];
    #pragma unroll
    for (int s = 0; s < 4; ++s) {
        const int c  = 2 * s + kh;
        const int kb = yidx_cm(frow, c);
        bkh[s] = *reinterpret_cast<bf16x8*>(&yhi[kb]);
        bkl[s] = *reinterpret_cast<bf16x8*>(&ylo[kb]);
    }
    if (w == 0) {
        #pragma unroll
        for (int s = 0; s < 4; ++s) { amh[s] = bkh[s]; aml[s] = bkl[s]; }
    } else {
        #pragma unroll
        for (int s = 0; s < 4; ++s) {
            const int c  = 2 * s + kh;
            const int mb = yidx_cm(32 + frow, c);
            amh[s] = *reinterpret_cast<bf16x8*>(&yhi[mb]);
            aml[s] = *reinterpret_cast<bf16x8*>(&ylo[mb]);
        }
    }

    f32x16 acc = {};
    #pragma unroll
    for (int s = 0; s < 4; ++s)
        acc = __builtin_amdgcn_mfma_f32_32x32x16_bf16(amh[s], bkh[s], acc, 0, 0, 0);
    #pragma unroll
    for (int s = 0; s < 4; ++s)
        acc = __builtin_amdgcn_mfma_f32_32x32x16_bf16(amh[s], bkl[s], acc, 0, 0, 0);
    #pragma unroll
    for (int s = 0; s < 4; ++s)
        acc = __builtin_amdgcn_mfma_f32_32x32x16_bf16(aml[s], bkh[s], acc, 0, 0, 0);

    const float nk  = nrm[frow];
    const int   mb0 = w * 32 + 4 * kh;
    float s = 0.f;
    #pragma unroll
    for (int r = 0; r < 16; ++r) {
        const float nm = nrm[mb0 + (r & 3) + 8 * (r >> 2)];
        const float sq = __builtin_fmaf(-2.0f, acc[r], nm + nk);
        s += __builtin_amdgcn_sqrtf(__builtin_fabsf(sq) + EPS);
    }
    s += __shfl_xor(s, 32);
    if (l < 32) pdist[w * 32 + l] = s;
    __syncthreads();

    const float dsum = pdist[frow] + pdist[32 + frow];
    float dmin = dsum;
    #pragma unroll
    for (int m = 1; m <= 16; m <<= 1) dmin = fminf(dmin, __shfl_xor(dmin, m));
    const float ez = __expf(dmin - dsum);
    float Z = ez;
    #pragma unroll
    for (int m = 1; m <= 16; m <<= 1) Z += __shfl_xor(Z, m);
    if (t < 32) wsh[frow] = ez * (64.0f / Z);
    __syncthreads();

    const int oc = l >> 3;
    const int ow = l & 7;
    float o = 0.f;
    #pragma unroll
    for (int kk = 0; kk < 16; ++kk) {
        const int kx = w * 16 + kk;
        const int bi = yidx_cm(kx, oc) + ow;
        const float f = __uint_as_float((unsigned)yhi[bi] << 16)
                      + __uint_as_float((unsigned)ylo[bi] << 16);
        o += wsh[kx] * f;
    }
    if (w == 1) obuf[l] = o;
    __syncthreads();
    if (w == 0) out[(size_t)n * D + l] = o + obuf[l];
}

extern "C" void kernel_launch(void* const* d_in, const int* in_sizes, int n_in,
                              void* d_out, int out_size, void* d_ws, size_t ws_size,
                              hipStream_t stream) {
    const float* x   = (const float*)d_in[0];
    const int*   nbr = (const int*)d_in[1];
    float*       out = (float*)d_out;
    const int n_nodes = in_sizes[0] / D;   // 20000
    const size_t need = (size_t)n_nodes * D * 2 * sizeof(unsigned short)
                      + (size_t)n_nodes * sizeof(float);
    if (d_ws != nullptr && ws_size >= need && (n_nodes % 2) == 0) {
        unsigned short* xhi  = (unsigned short*)d_ws;
        unsigned short* xlo  = xhi + (size_t)n_nodes * D;
        float*          xnrm = (float*)(xlo + (size_t)n_nodes * D);
        const int tasks = n_nodes * 8;
        rgc_prep<<<(tasks + 255) / 256, 256, 0, stream>>>(x, xhi, xlo, xnrm, n_nodes);
        rgc_main<<<n_nodes / 2, 128, 0, stream>>>(xhi, xlo, xnrm, nbr, out);
    } else {
        rgc_fallback<<<n_nodes, 128, 0, stream>>>(x, nbr, out);
    }
}

// Round 12
// 30.972 us; speedup vs baseline: 1.6250x; 1.4871x over previous
//
#include <hip/hip_runtime.h>
#include <math.h>

typedef float f32x16 __attribute__((ext_vector_type(16)));
typedef _Float16 f16x8 __attribute__((ext_vector_type(8)));
typedef __bf16 bf16x8 __attribute__((ext_vector_type(8)));

constexpr int DEG = 64;
constexpr int KC  = 32;
constexpr int D   = 64;
constexpr float EPS = 1.1920929e-05f;  // 100 * f32 eps

// LDS layout: row-major [64 rows][8 chunks of 16B], chunk c of row r at slot
// (c ^ (r&7)) -> ushort idx = row*64 + slot*8. Staged via global_load_lds with
// pre-permuted SOURCE chunk sc=(l&7)^(l>>3), linear dest (both-sides rule).
__device__ __forceinline__ int yidx(int row, int c) {
    return (row << 6) + (((c ^ (row & 7)) & 7) << 3);
}

__device__ __forceinline__ float f16_bits_to_f32(unsigned short u) {
    return (float)__builtin_bit_cast(_Float16, u);
}

// ---- prep: x(f32) -> xh(f16, row-major) + norms OF THE QUANTIZED values ----
// Norms-of-quantized => sq = nm+nk-2*dot cancels EXACTLY at duplicate rows
// (f16 products are exact in the MFMA f32 accumulator), so no lo term needed.
__global__ __launch_bounds__(256)
void rgc_prep(const float* __restrict__ x,
              unsigned short* __restrict__ xh,
              float* __restrict__ xnrm, int nrows) {
    const int id  = blockIdx.x * 256 + threadIdx.x;
    const int row = id >> 3;
    const int c   = id & 7;
    if (row >= nrows) return;
    const float* src = x + ((size_t)row << 6) + (c << 3);
    const float4 v0 = *reinterpret_cast<const float4*>(src);
    const float4 v1 = *reinterpret_cast<const float4*>(src + 4);
    const float fv[8] = {v0.x, v0.y, v0.z, v0.w, v1.x, v1.y, v1.z, v1.w};
    f16x8 h;
    float s = 0.f;
    #pragma unroll
    for (int j = 0; j < 8; ++j) {
        h[j] = (_Float16)fv[j];        // RNE
        const float hf = (float)h[j];
        s += hf * hf;                  // norm of quantized row
    }
    s += __shfl_xor(s, 1); s += __shfl_xor(s, 2); s += __shfl_xor(s, 4);
    if (c == 0) xnrm[row] = s;
    *reinterpret_cast<f16x8*>(xh + ((size_t)row << 6) + (c << 3)) = h;
}

// ------- main: 2 independent waves/block (2 nodes), 8 KB LDS each, no barriers -------
__global__ __launch_bounds__(128, 4)
void rgc_main(const unsigned short* __restrict__ xh,
              const float* __restrict__ xnrm,
              const int*   __restrict__ nbr,
              float*       __restrict__ out) {
    __shared__ __align__(16) unsigned short yh[2][4096];  // 8 KB per wave
    __shared__ __align__(16) float wtab[2][32];           // per-wave softmax weights

    const int t  = threadIdx.x;
    const int wv = t >> 6;
    const int l  = t & 63;
    const long node = (long)blockIdx.x * 2 + wv;

    const int my = nbr[node * 64 + l];

    const int frow = l & 31;
    const int kh   = l >> 5;

    // ---- staging FIRST: instr j covers rows 8j..8j+7 fully (16 lines/instr) ----
    unsigned short* yb = &yh[wv][0];
    const int sc = (l & 7) ^ (l >> 3);   // source chunk -> lands at slot l&7
    #pragma unroll
    for (int j = 0; j < 8; ++j) {
        const int g = __shfl(my, 8 * j + (l >> 3));
        const size_t so = ((size_t)g << 6) + (sc << 3);
        __builtin_amdgcn_global_load_lds(
            (const __attribute__((address_space(1))) unsigned int*)(xh + so),
            (__attribute__((address_space(3))) unsigned int*)(yb + (j << 9)),
            16, 0, 0);
    }
    __builtin_amdgcn_sched_barrier(0);   // pin: staging issued before xnrm loads

    // ---- norms (plain loads, compiler-tracked) ----
    const int gb = __shfl(my, frow);          // k-row id (= tile0 m-row id)
    const int ga = __shfl(my, 32 + frow);     // tile1 m-row id
    const float nk = xnrm[gb];
    const float na = xnrm[ga];
    __builtin_amdgcn_sched_barrier(0);

    // 8 staging + 2 xnrm outstanding; vmcnt(2) drains exactly the 8 staging
    asm volatile("s_waitcnt vmcnt(2)" ::: "memory");
    __builtin_amdgcn_sched_barrier(0);

    // ---- fragments from LDS: D = Xm·Xk^T; k = lane dim, m = reg dim ----
    f16x8 bh[4], ah2[4];
    #pragma unroll
    for (int s = 0; s < 4; ++s) {
        const int c = 2 * s + kh;
        bh[s]  = *reinterpret_cast<const f16x8*>(&yb[yidx(frow, c)]);
        ah2[s] = *reinterpret_cast<const f16x8*>(&yb[yidx(32 + frow, c)]);
    }

    f32x16 acc0 = {}, acc1 = {};
    #pragma unroll
    for (int s = 0; s < 4; ++s) {
        acc0 = __builtin_amdgcn_mfma_f32_32x32x16_f16(bh[s],  bh[s], acc0, 0, 0, 0);
        acc1 = __builtin_amdgcn_mfma_f32_32x32x16_f16(ah2[s], bh[s], acc1, 0, 0, 0);
    }

    // ---- aug slab: A(m)=[nm_h,nm_l,1,1], B(k)=[-0.5,-0.5,mnk_h,mnk_l] ----
    // acc += -0.5*(nm+nk); f16 hi/lo pair carries nm to ~2^-22.
    f16x8 Bg = {}, A0 = {}, A1 = {};
    {
        const float mnk = -0.5f * nk;
        const _Float16 mnk_h = (_Float16)mnk;
        if (kh == 0) {
            Bg[0] = (_Float16)(-0.5f); Bg[1] = (_Float16)(-0.5f);
            Bg[2] = mnk_h;             Bg[3] = (_Float16)(mnk - (float)mnk_h);
            const _Float16 nk_h = (_Float16)nk;
            A0[0] = nk_h; A0[1] = (_Float16)(nk - (float)nk_h);
            A0[2] = (_Float16)1.0f; A0[3] = (_Float16)1.0f;
            const _Float16 na_h = (_Float16)na;
            A1[0] = na_h; A1[1] = (_Float16)(na - (float)na_h);
            A1[2] = (_Float16)1.0f; A1[3] = (_Float16)1.0f;
        }
    }
    acc0 = __builtin_amdgcn_mfma_f32_32x32x16_f16(A0, Bg, acc0, 0, 0, 0);
    acc1 = __builtin_amdgcn_mfma_f32_32x32x16_f16(A1, Bg, acc1, 0, 0, 0);

    // ---- l2 + dist: sq = -2*acc -> |sq|+EPS = 2|acc|+EPS; 4-way sum tree ----
    float s0 = 0.f, s1 = 0.f, s2 = 0.f, s3 = 0.f;
    #pragma unroll
    for (int r = 0; r < 16; r += 4) {
        s0 += __builtin_amdgcn_sqrtf(__builtin_fmaf(2.0f, __builtin_fabsf(acc0[r + 0]), EPS));
        s1 += __builtin_amdgcn_sqrtf(__builtin_fmaf(2.0f, __builtin_fabsf(acc0[r + 1]), EPS));
        s2 += __builtin_amdgcn_sqrtf(__builtin_fmaf(2.0f, __builtin_fabsf(acc0[r + 2]), EPS));
        s3 += __builtin_amdgcn_sqrtf(__builtin_fmaf(2.0f, __builtin_fabsf(acc0[r + 3]), EPS));
    }
    #pragma unroll
    for (int r = 0; r < 16; r += 4) {
        s0 += __builtin_amdgcn_sqrtf(__builtin_fmaf(2.0f, __builtin_fabsf(acc1[r + 0]), EPS));
        s1 += __builtin_amdgcn_sqrtf(__builtin_fmaf(2.0f, __builtin_fabsf(acc1[r + 1]), EPS));
        s2 += __builtin_amdgcn_sqrtf(__builtin_fmaf(2.0f, __builtin_fabsf(acc1[r + 2]), EPS));
        s3 += __builtin_amdgcn_sqrtf(__builtin_fmaf(2.0f, __builtin_fabsf(acc1[r + 3]), EPS));
    }
    float s = (s0 + s1) + (s2 + s3);
    s += __shfl_xor(s, 32);   // full dist_k at lanes k and k+32

    // ---- softmax over 32 candidates (in-wave, replicated across halves) ----
    float dmin = s;
    #pragma unroll
    for (int m = 1; m <= 16; m <<= 1) dmin = fminf(dmin, __shfl_xor(dmin, m));
    const float ez = __expf(dmin - s);
    float Z = ez;
    #pragma unroll
    for (int m = 1; m <= 16; m <<= 1) Z += __shfl_xor(Z, m);
    const float ezs = ez * (64.0f / Z);   // lane k holds w_k (row_sum = DEG)

    // ---- epilogue: w via LDS broadcast table; f16 reconstruction ----
    if (l < 32) wtab[wv][l] = ezs;
    asm volatile("s_waitcnt lgkmcnt(0)" ::: "memory");
    __builtin_amdgcn_sched_barrier(0);

    const int klo = kh << 4;
    const float4 w0 = *reinterpret_cast<const float4*>(&wtab[wv][klo + 0]);
    const float4 w1 = *reinterpret_cast<const float4*>(&wtab[wv][klo + 4]);
    const float4 w2 = *reinterpret_cast<const float4*>(&wtab[wv][klo + 8]);
    const float4 w3 = *reinterpret_cast<const float4*>(&wtab[wv][klo + 12]);
    const float wreg[16] = {w0.x, w0.y, w0.z, w0.w, w1.x, w1.y, w1.z, w1.w,
                            w2.x, w2.y, w2.z, w2.w, w3.x, w3.y, w3.z, w3.w};

    const int d0 = (l & 31) << 1;
    float oe = 0.f, oo = 0.f;
    #pragma unroll
    for (int kk = 0; kk < 16; ++kk) {
        const int k  = klo + kk;
        const float wk = wreg[kk];
        const int idx = (k << 6) + ((((d0 >> 3) ^ (k & 7)) & 7) << 3) + (d0 & 7);
        const unsigned uh = *reinterpret_cast<const unsigned*>(&yb[idx]);
        oe = __builtin_fmaf(wk, f16_bits_to_f32((unsigned short)(uh & 0xffffu)), oe);
        oo = __builtin_fmaf(wk, f16_bits_to_f32((unsigned short)(uh >> 16)), oo);
    }
    oe += __shfl_xor(oe, 32);
    oo += __shfl_xor(oo, 32);
    if (l < 32) {
        float2 v = make_float2(oe, oo);
        *reinterpret_cast<float2*>(out + ((size_t)node << 6) + (l << 1)) = v;
    }
}

// ---------------- fallback (no workspace): R4 path, bf16 hi/lo ----------------
__device__ __forceinline__ int yidx_cm(int row, int chunk) {  // old chunk-major
    return (chunk << 9) + ((row ^ chunk) << 3);
}

__global__ __launch_bounds__(128, 4)
void rgc_fallback(const float* __restrict__ x,
                  const int*   __restrict__ nbr,
                  float*       __restrict__ out) {
    __shared__ __align__(16) unsigned short yhi[4096];
    __shared__ __align__(16) unsigned short ylo[4096];
    __shared__ float nrm[64];
    __shared__ float wsh[KC];
    __shared__ float pdist[64];
    __shared__ float obuf[64];

    const int n = blockIdx.x;
    const int t = threadIdx.x;
    const int w = t >> 6;
    const int l = t & 63;

    const int srow = t >> 3;
    const int sc   = t & 7;
    int gidx[4];
    #pragma unroll
    for (int it = 0; it < 4; ++it)
        gidx[it] = nbr[(n << 6) + it * 16 + srow];

    #pragma unroll
    for (int it = 0; it < 4; ++it) {
        const int row = it * 16 + srow;
        const float* src = x + ((size_t)gidx[it] << 6) + (sc << 3);
        const float4 v0 = *reinterpret_cast<const float4*>(src);
        const float4 v1 = *reinterpret_cast<const float4*>(src + 4);
        const float fv[8] = {v0.x, v0.y, v0.z, v0.w, v1.x, v1.y, v1.z, v1.w};
        float s = 0.f;
        bf16x8 h, e;
        #pragma unroll
        for (int j = 0; j < 8; ++j) {
            const float f = fv[j];
            s += f * f;
            const __bf16 hb = (__bf16)f;
            h[j] = hb;
            e[j] = (__bf16)(f - (float)hb);
        }
        s += __shfl_xor(s, 1); s += __shfl_xor(s, 2); s += __shfl_xor(s, 4);
        if (sc == 0) nrm[row] = s;
        const int base = yidx_cm(row, sc);
        *reinterpret_cast<bf16x8*>(&yhi[base]) = h;
        *reinterpret_cast<bf16x8*>(&ylo[base]) = e;
    }
    __syncthreads();

    const int frow = l & 31;
    const int kh   = l >> 5;
    bf16x8 amh[4], aml[4], bkh[4], bkl[4];
    #pragma unroll
    for (int s = 0; s < 4; ++s) {
        const int c  = 2 * s + kh;
        const int kb = yidx_cm(frow, c);
        bkh[s] = *reinterpret_cast<bf16x8*>(&yhi[kb]);
        bkl[s] = *reinterpret_cast<bf16x8*>(&ylo[kb]);
    }
    if (w == 0) {
        #pragma unroll
        for (int s = 0; s < 4; ++s) { amh[s] = bkh[s]; aml[s] = bkl[s]; }
    } else {
        #pragma unroll
        for (int s = 0; s < 4; ++s) {
            const int c  = 2 * s + kh;
            const int mb = yidx_cm(32 + frow, c);
            amh[s] = *reinterpret_cast<bf16x8*>(&yhi[mb]);
            aml[s] = *reinterpret_cast<bf16x8*>(&ylo[mb]);
        }
    }

    f32x16 acc = {};
    #pragma unroll
    for (int s = 0; s < 4; ++s)
        acc = __builtin_amdgcn_mfma_f32_32x32x16_bf16(amh[s], bkh[s], acc, 0, 0, 0);
    #pragma unroll
    for (int s = 0; s < 4; ++s)
        acc = __builtin_amdgcn_mfma_f32_32x32x16_bf16(amh[s], bkl[s], acc, 0, 0, 0);
    #pragma unroll
    for (int s = 0; s < 4; ++s)
        acc = __builtin_amdgcn_mfma_f32_32x32x16_bf16(aml[s], bkh[s], acc, 0, 0, 0);

    const float nk  = nrm[frow];
    const int   mb0 = w * 32 + 4 * kh;
    float s = 0.f;
    #pragma unroll
    for (int r = 0; r < 16; ++r) {
        const float nm = nrm[mb0 + (r & 3) + 8 * (r >> 2)];
        const float sq = __builtin_fmaf(-2.0f, acc[r], nm + nk);
        s += __builtin_amdgcn_sqrtf(__builtin_fabsf(sq) + EPS);
    }
    s += __shfl_xor(s, 32);
    if (l < 32) pdist[w * 32 + l] = s;
    __syncthreads();

    const float dsum = pdist[frow] + pdist[32 + frow];
    float dmin = dsum;
    #pragma unroll
    for (int m = 1; m <= 16; m <<= 1) dmin = fminf(dmin, __shfl_xor(dmin, m));
    const float ez = __expf(dmin - dsum);
    float Z = ez;
    #pragma unroll
    for (int m = 1; m <= 16; m <<= 1) Z += __shfl_xor(Z, m);
    if (t < 32) wsh[frow] = ez * (64.0f / Z);
    __syncthreads();

    const int oc = l >> 3;
    const int ow = l & 7;
    float o = 0.f;
    #pragma unroll
    for (int kk = 0; kk < 16; ++kk) {
        const int kx = w * 16 + kk;
        const int bi = yidx_cm(kx, oc) + ow;
        const float f = __uint_as_float((unsigned)yhi[bi] << 16)
                      + __uint_as_float((unsigned)ylo[bi] << 16);
        o += wsh[kx] * f;
    }
    if (w == 1) obuf[l] = o;
    __syncthreads();
    if (w == 0) out[(size_t)n * D + l] = o + obuf[l];
}

extern "C" void kernel_launch(void* const* d_in, const int* in_sizes, int n_in,
                              void* d_out, int out_size, void* d_ws, size_t ws_size,
                              hipStream_t stream) {
    const float* x   = (const float*)d_in[0];
    const int*   nbr = (const int*)d_in[1];
    float*       out = (float*)d_out;
    const int n_nodes = in_sizes[0] / D;   // 20000
    const size_t need = (size_t)n_nodes * D * sizeof(unsigned short)
                      + (size_t)n_nodes * sizeof(float);
    if (d_ws != nullptr && ws_size >= need && (n_nodes % 2) == 0) {
        unsigned short* xh   = (unsigned short*)d_ws;
        float*          xnrm = (float*)(xh + (size_t)n_nodes * D);
        const int tasks = n_nodes * 8;
        rgc_prep<<<(tasks + 255) / 256, 256, 0, stream>>>(x, xh, xnrm, n_nodes);
        rgc_main<<<n_nodes / 2, 128, 0, stream>>>(xh, xnrm, nbr, out);
    } else {
        rgc_fallback<<<n_nodes, 128, 0, stream>>>(x, nbr, out);
    }
}

// Round 14
// 30.364 us; speedup vs baseline: 1.6576x; 1.0200x over previous
//
#include <hip/hip_runtime.h>
#include <math.h>

typedef float f32x16 __attribute__((ext_vector_type(16)));
typedef _Float16 f16x8 __attribute__((ext_vector_type(8)));
typedef __bf16 bf16x8 __attribute__((ext_vector_type(8)));

constexpr int DEG = 64;
constexpr int KC  = 32;
constexpr int D   = 64;
constexpr float EPS = 1.1920929e-05f;  // 100 * f32 eps

// LDS layout: row-major [64 rows][8 chunks of 16B], chunk c of row r at slot
// (c ^ (r&7)) -> ushort idx = row*64 + slot*8. Staged via global_load_lds with
// pre-permuted SOURCE chunk sc=(l&7)^(l>>3), linear dest (both-sides rule).
__device__ __forceinline__ int yidx(int row, int c) {
    return (row << 6) + (((c ^ (row & 7)) & 7) << 3);
}

__device__ __forceinline__ float f16_bits_to_f32(unsigned short u) {
    return (float)__builtin_bit_cast(_Float16, u);
}

// ---- prep: x(f32) -> xh(f16, row-major) + norms OF THE QUANTIZED values ----
// Norms-of-quantized => sq = nm+nk-2*dot cancels EXACTLY at duplicate rows
// (f16 products are exact in the MFMA f32 accumulator), so no lo term needed.
__global__ __launch_bounds__(256)
void rgc_prep(const float* __restrict__ x,
              unsigned short* __restrict__ xh,
              float* __restrict__ xnrm, int nrows) {
    const int id  = blockIdx.x * 256 + threadIdx.x;
    const int row = id >> 3;
    const int c   = id & 7;
    if (row >= nrows) return;
    const float* src = x + ((size_t)row << 6) + (c << 3);
    const float4 v0 = *reinterpret_cast<const float4*>(src);
    const float4 v1 = *reinterpret_cast<const float4*>(src + 4);
    const float fv[8] = {v0.x, v0.y, v0.z, v0.w, v1.x, v1.y, v1.z, v1.w};
    f16x8 h;
    float s = 0.f;
    #pragma unroll
    for (int j = 0; j < 8; ++j) {
        h[j] = (_Float16)fv[j];        // RNE
        const float hf = (float)h[j];
        s += hf * hf;                  // norm of quantized row
    }
    s += __shfl_xor(s, 1); s += __shfl_xor(s, 2); s += __shfl_xor(s, 4);
    if (c == 0) xnrm[row] = s;
    *reinterpret_cast<f16x8*>(xh + ((size_t)row << 6) + (c << 3)) = h;
}

// ------- main: 2 independent waves/block (2 nodes), 8 KB LDS each, no barriers -------
__global__ __launch_bounds__(128, 4)
void rgc_main(const unsigned short* __restrict__ xh,
              const float* __restrict__ xnrm,
              const int*   __restrict__ nbr,
              float*       __restrict__ out) {
    __shared__ __align__(16) unsigned short yh[2][4096];  // 8 KB per wave
    __shared__ __align__(16) float wtab[2][32];           // per-wave softmax weights

    const int t  = threadIdx.x;
    const int wv = t >> 6;
    const int l  = t & 63;
    const long node = (long)blockIdx.x * 2 + wv;

    const int my = nbr[node * 64 + l];

    const int frow = l & 31;
    const int kh   = l >> 5;

    // ---- staging FIRST: instr j covers rows 8j..8j+7 fully (16 lines/instr) ----
    unsigned short* yb = &yh[wv][0];
    const int sc = (l & 7) ^ (l >> 3);   // source chunk -> lands at slot l&7
    #pragma unroll
    for (int j = 0; j < 8; ++j) {
        const int g = __shfl(my, 8 * j + (l >> 3));
        const size_t so = ((size_t)g << 6) + (sc << 3);
        __builtin_amdgcn_global_load_lds(
            (const __attribute__((address_space(1))) unsigned int*)(xh + so),
            (__attribute__((address_space(3))) unsigned int*)(yb + (j << 9)),
            16, 0, 0);
    }
    __builtin_amdgcn_sched_barrier(0);   // pin: staging issued before xnrm loads

    // ---- norms (plain loads, compiler-tracked) ----
    const int gb = __shfl(my, frow);          // k-row id (= tile0 m-row id)
    const int ga = __shfl(my, 32 + frow);     // tile1 m-row id
    const float nk = xnrm[gb];
    const float na = xnrm[ga];
    __builtin_amdgcn_sched_barrier(0);

    // 8 staging + 2 xnrm outstanding; vmcnt(2) drains exactly the 8 staging
    asm volatile("s_waitcnt vmcnt(2)" ::: "memory");
    __builtin_amdgcn_sched_barrier(0);

    // ---- fragments from LDS: D = Xm·Xk^T; k = lane dim, m = reg dim ----
    f16x8 bh[4], ah2[4];
    #pragma unroll
    for (int s = 0; s < 4; ++s) {
        const int c = 2 * s + kh;
        bh[s]  = *reinterpret_cast<const f16x8*>(&yb[yidx(frow, c)]);
        ah2[s] = *reinterpret_cast<const f16x8*>(&yb[yidx(32 + frow, c)]);
    }

    f32x16 acc0 = {}, acc1 = {};
    #pragma unroll
    for (int s = 0; s < 4; ++s) {
        acc0 = __builtin_amdgcn_mfma_f32_32x32x16_f16(bh[s],  bh[s], acc0, 0, 0, 0);
        acc1 = __builtin_amdgcn_mfma_f32_32x32x16_f16(ah2[s], bh[s], acc1, 0, 0, 0);
    }

    // ---- aug slab: A(m)=[nm_h,nm_l,1,1], B(k)=[-0.5,-0.5,mnk_h,mnk_l] ----
    f16x8 Bg = {}, A0 = {}, A1 = {};
    {
        const float mnk = -0.5f * nk;
        const _Float16 mnk_h = (_Float16)mnk;
        if (kh == 0) {
            Bg[0] = (_Float16)(-0.5f); Bg[1] = (_Float16)(-0.5f);
            Bg[2] = mnk_h;             Bg[3] = (_Float16)(mnk - (float)mnk_h);
            const _Float16 nk_h = (_Float16)nk;
            A0[0] = nk_h; A0[1] = (_Float16)(nk - (float)nk_h);
            A0[2] = (_Float16)1.0f; A0[3] = (_Float16)1.0f;
            const _Float16 na_h = (_Float16)na;
            A1[0] = na_h; A1[1] = (_Float16)(na - (float)na_h);
            A1[2] = (_Float16)1.0f; A1[3] = (_Float16)1.0f;
        }
    }
    acc0 = __builtin_amdgcn_mfma_f32_32x32x16_f16(A0, Bg, acc0, 0, 0, 0);
    acc1 = __builtin_amdgcn_mfma_f32_32x32x16_f16(A1, Bg, acc1, 0, 0, 0);

    // ---- PRELOAD epilogue Y-columns (independent of softmax; their LDS
    //      latency hides under the reduction chains below) ----
    const int klo = kh << 4;
    const int d0 = (l & 31) << 1;
    unsigned pre[16];
    #pragma unroll
    for (int kk = 0; kk < 16; ++kk) {
        const int k  = klo + kk;
        const int idx = (k << 6) + ((((d0 >> 3) ^ (k & 7)) & 7) << 3) + (d0 & 7);
        pre[kk] = *reinterpret_cast<const unsigned*>(&yb[idx]);
    }

    // ---- l2 + dist: sq = -2*acc -> |sq|+EPS = 2|acc|+EPS; 4-way sum tree ----
    float s0 = 0.f, s1 = 0.f, s2 = 0.f, s3 = 0.f;
    #pragma unroll
    for (int r = 0; r < 16; r += 4) {
        s0 += __builtin_amdgcn_sqrtf(__builtin_fmaf(2.0f, __builtin_fabsf(acc0[r + 0]), EPS));
        s1 += __builtin_amdgcn_sqrtf(__builtin_fmaf(2.0f, __builtin_fabsf(acc0[r + 1]), EPS));
        s2 += __builtin_amdgcn_sqrtf(__builtin_fmaf(2.0f, __builtin_fabsf(acc0[r + 2]), EPS));
        s3 += __builtin_amdgcn_sqrtf(__builtin_fmaf(2.0f, __builtin_fabsf(acc0[r + 3]), EPS));
    }
    #pragma unroll
    for (int r = 0; r < 16; r += 4) {
        s0 += __builtin_amdgcn_sqrtf(__builtin_fmaf(2.0f, __builtin_fabsf(acc1[r + 0]), EPS));
        s1 += __builtin_amdgcn_sqrtf(__builtin_fmaf(2.0f, __builtin_fabsf(acc1[r + 1]), EPS));
        s2 += __builtin_amdgcn_sqrtf(__builtin_fmaf(2.0f, __builtin_fabsf(acc1[r + 2]), EPS));
        s3 += __builtin_amdgcn_sqrtf(__builtin_fmaf(2.0f, __builtin_fabsf(acc1[r + 3]), EPS));
    }
    float s = (s0 + s1) + (s2 + s3);
    s += __shfl_xor(s, 32);   // full dist_k at lanes k and k+32

    // ---- softmax over 32 candidates (safe min-bias; R12-proven numerics) ----
    float dmin = s;
    #pragma unroll
    for (int m = 1; m <= 16; m <<= 1) dmin = fminf(dmin, __shfl_xor(dmin, m));
    const float ez = __expf(dmin - s);
    float Z = ez;
    #pragma unroll
    for (int m = 1; m <= 16; m <<= 1) Z += __shfl_xor(Z, m);
    const float ezs = ez * (64.0f / Z);   // lane k holds w_k (row_sum = DEG)

    // ---- epilogue: w via LDS broadcast table; pure FMAs on preloaded Y ----
    if (l < 32) wtab[wv][l] = ezs;
    asm volatile("s_waitcnt lgkmcnt(0)" ::: "memory");
    __builtin_amdgcn_sched_barrier(0);

    const float4 w0 = *reinterpret_cast<const float4*>(&wtab[wv][klo + 0]);
    const float4 w1 = *reinterpret_cast<const float4*>(&wtab[wv][klo + 4]);
    const float4 w2 = *reinterpret_cast<const float4*>(&wtab[wv][klo + 8]);
    const float4 w3 = *reinterpret_cast<const float4*>(&wtab[wv][klo + 12]);
    const float wreg[16] = {w0.x, w0.y, w0.z, w0.w, w1.x, w1.y, w1.z, w1.w,
                            w2.x, w2.y, w2.z, w2.w, w3.x, w3.y, w3.z, w3.w};

    float oe = 0.f, oo = 0.f;
    #pragma unroll
    for (int kk = 0; kk < 16; ++kk) {
        const float wk = wreg[kk];
        const unsigned uh = pre[kk];
        oe = __builtin_fmaf(wk, f16_bits_to_f32((unsigned short)(uh & 0xffffu)), oe);
        oo = __builtin_fmaf(wk, f16_bits_to_f32((unsigned short)(uh >> 16)), oo);
    }
    oe += __shfl_xor(oe, 32);
    oo += __shfl_xor(oo, 32);
    if (l < 32) {
        float2 v = make_float2(oe, oo);
        *reinterpret_cast<float2*>(out + ((size_t)node << 6) + (l << 1)) = v;
    }
}

// ---------------- fallback (no workspace): R4 path, bf16 hi/lo ----------------
__device__ __forceinline__ int yidx_cm(int row, int chunk) {  // old chunk-major
    return (chunk << 9) + ((row ^ chunk) << 3);
}

__global__ __launch_bounds__(128, 4)
void rgc_fallback(const float* __restrict__ x,
                  const int*   __restrict__ nbr,
                  float*       __restrict__ out) {
    __shared__ __align__(16) unsigned short yhi[4096];
    __shared__ __align__(16) unsigned short ylo[4096];
    __shared__ float nrm[64];
    __shared__ float wsh[KC];
    __shared__ float pdist[64];
    __shared__ float obuf[64];

    const int n = blockIdx.x;
    const int t = threadIdx.x;
    const int w = t >> 6;
    const int l = t & 63;

    const int srow = t >> 3;
    const int sc   = t & 7;
    int gidx[4];
    #pragma unroll
    for (int it = 0; it < 4; ++it)
        gidx[it] = nbr[(n << 6) + it * 16 + srow];

    #pragma unroll
    for (int it = 0; it < 4; ++it) {
        const int row = it * 16 + srow;
        const float* src = x + ((size_t)gidx[it] << 6) + (sc << 3);
        const float4 v0 = *reinterpret_cast<const float4*>(src);
        const float4 v1 = *reinterpret_cast<const float4*>(src + 4);
        const float fv[8] = {v0.x, v0.y, v0.z, v0.w, v1.x, v1.y, v1.z, v1.w};
        float s = 0.f;
        bf16x8 h, e;
        #pragma unroll
        for (int j = 0; j < 8; ++j) {
            const float f = fv[j];
            s += f * f;
            const __bf16 hb = (__bf16)f;
            h[j] = hb;
            e[j] = (__bf16)(f - (float)hb);
        }
        s += __shfl_xor(s, 1); s += __shfl_xor(s, 2); s += __shfl_xor(s, 4);
        if (sc == 0) nrm[row] = s;
        const int base = yidx_cm(row, sc);
        *reinterpret_cast<bf16x8*>(&yhi[base]) = h;
        *reinterpret_cast<bf16x8*>(&ylo[base]) = e;
    }
    __syncthreads();

    const int frow = l & 31;
    const int kh   = l >> 5;
    bf16x8 amh[4], aml[4], bkh[4], bkl[4];
    #pragma unroll
    for (int s = 0; s < 4; ++s) {
        const int c  = 2 * s + kh;
        const int kb = yidx_cm(frow, c);
        bkh[s] = *reinterpret_cast<bf16x8*>(&yhi[kb]);
        bkl[s] = *reinterpret_cast<bf16x8*>(&ylo[kb]);
    }
    if (w == 0) {
        #pragma unroll
        for (int s = 0; s < 4; ++s) { amh[s] = bkh[s]; aml[s] = bkl[s]; }
    } else {
        #pragma unroll
        for (int s = 0; s < 4; ++s) {
            const int c  = 2 * s + kh;
            const int mb = yidx_cm(32 + frow, c);
            amh[s] = *reinterpret_cast<bf16x8*>(&yhi[mb]);
            aml[s] = *reinterpret_cast<bf16x8*>(&ylo[mb]);
        }
    }

    f32x16 acc = {};
    #pragma unroll
    for (int s = 0; s < 4; ++s)
        acc = __builtin_amdgcn_mfma_f32_32x32x16_bf16(amh[s], bkh[s], acc, 0, 0, 0);
    #pragma unroll
    for (int s = 0; s < 4; ++s)
        acc = __builtin_amdgcn_mfma_f32_32x32x16_bf16(amh[s], bkl[s], acc, 0, 0, 0);
    #pragma unroll
    for (int s = 0; s < 4; ++s)
        acc = __builtin_amdgcn_mfma_f32_32x32x16_bf16(aml[s], bkh[s], acc, 0, 0, 0);

    const float nk  = nrm[frow];
    const int   mb0 = w * 32 + 4 * kh;
    float s = 0.f;
    #pragma unroll
    for (int r = 0; r < 16; ++r) {
        const float nm = nrm[mb0 + (r & 3) + 8 * (r >> 2)];
        const float sq = __builtin_fmaf(-2.0f, acc[r], nm + nk);
        s += __builtin_amdgcn_sqrtf(__builtin_fabsf(sq) + EPS);
    }
    s += __shfl_xor(s, 32);
    if (l < 32) pdist[w * 32 + l] = s;
    __syncthreads();

    const float dsum = pdist[frow] + pdist[32 + frow];
    float dmin = dsum;
    #pragma unroll
    for (int m = 1; m <= 16; m <<= 1) dmin = fminf(dmin, __shfl_xor(dmin, m));
    const float ez = __expf(dmin - dsum);
    float Z = ez;
    #pragma unroll
    for (int m = 1; m <= 16; m <<= 1) Z += __shfl_xor(Z, m);
    if (t < 32) wsh[frow] = ez * (64.0f / Z);
    __syncthreads();

    const int oc = l >> 3;
    const int ow = l & 7;
    float o = 0.f;
    #pragma unroll
    for (int kk = 0; kk < 16; ++kk) {
        const int kx = w * 16 + kk;
        const int bi = yidx_cm(kx, oc) + ow;
        const float f = __uint_as_float((unsigned)yhi[bi] << 16)
                      + __uint_as_float((unsigned)ylo[bi] << 16);
        o += wsh[kx] * f;
    }
    if (w == 1) obuf[l] = o;
    __syncthreads();
    if (w == 0) out[(size_t)n * D + l] = o + obuf[l];
}

extern "C" void kernel_launch(void* const* d_in, const int* in_sizes, int n_in,
                              void* d_out, int out_size, void* d_ws, size_t ws_size,
                              hipStream_t stream) {
    const float* x   = (const float*)d_in[0];
    const int*   nbr = (const int*)d_in[1];
    float*       out = (float*)d_out;
    const int n_nodes = in_sizes[0] / D;   // 20000
    const size_t need = (size_t)n_nodes * D * sizeof(unsigned short)
                      + (size_t)n_nodes * sizeof(float);
    if (d_ws != nullptr && ws_size >= need && (n_nodes % 2) == 0) {
        unsigned short* xh   = (unsigned short*)d_ws;
        float*          xnrm = (float*)(xh + (size_t)n_nodes * D);
        const int tasks = n_nodes * 8;
        rgc_prep<<<(tasks + 255) / 256, 256, 0, stream>>>(x, xh, xnrm, n_nodes);
        rgc_main<<<n_nodes / 2, 128, 0, stream>>>(xh, xnrm, nbr, out);
    } else {
        rgc_fallback<<<n_nodes, 128, 0, stream>>>(x, nbr, out);
    }
}